// Round 1
// baseline (366.068 us; speedup 1.0000x reference)
//
#include <hip/hip_runtime.h>
#include <hip/hip_bf16.h>

typedef __bf16 bf16x8 __attribute__((ext_vector_type(8)));
typedef float f32x4 __attribute__((ext_vector_type(4)));

#define HH 112
#define WW 112
#define CIN 128
#define COUT 128

#define RR 18          // staged region rows (16 + 2 halo)
#define RC 18          // staged region cols
#define CSTRIDE 40     // 32 channels + 8 pad -> 80B cell stride, 16B aligned frags

// Repack weights: w[o][c][ky][kx] f32  ->  wb[ky*3+kx][o][c] bf16
__global__ void wino_prep_weights(const float* __restrict__ w,
                                  __hip_bfloat16* __restrict__ wb) {
    int t = blockIdx.x * 256 + threadIdx.x;
    if (t >= 9 * COUT * CIN) return;
    int c = t & (CIN - 1);
    int o = (t >> 7) & (COUT - 1);
    int r = t >> 14;                       // tap index 0..8
    wb[t] = __float2bfloat16(w[(o * CIN + c) * 9 + r]);
}

// Direct 3x3 conv as implicit GEMM with bf16 MFMA.
// Block: 256 threads = 4 waves. Output tile: 128 O x (16x16) pixels.
// wave wv: wo=wv>>1 selects o-half (64), wp=wv&1 selects p-half (128 px).
__global__ __launch_bounds__(256, 2) void conv3x3_mfma(
        const float* __restrict__ x, const __hip_bfloat16* __restrict__ wb,
        const float* __restrict__ bias, float* __restrict__ out) {
    __shared__ __align__(16) __hip_bfloat16 xs[RR * RC * CSTRIDE];

    const int bx = blockIdx.x, by = blockIdx.y, n = blockIdx.z;
    const int ox0 = bx * 16, oy0 = by * 16;
    const int tid = threadIdx.x;
    const int lane = tid & 63;
    const int wv = tid >> 6;
    const int wo = wv >> 1;
    const int wp = wv & 1;
    const int l15 = lane & 15;
    const int lg = lane >> 4;              // 0..3, k-group

    f32x4 acc[4][8];
#pragma unroll
    for (int i = 0; i < 4; ++i)
#pragma unroll
        for (int j = 0; j < 8; ++j)
            acc[i][j] = (f32x4){0.f, 0.f, 0.f, 0.f};

#pragma unroll 1
    for (int cc = 0; cc < 4; ++cc) {
        if (cc) __syncthreads();
        const int cbase = cc * 32;
        // Stage 32 channels of the 18x18 halo region, transposed to [row][col][c] bf16.
        // 576 (row,c) pairs; each thread handles up to 3, 18 cols each.
#pragma unroll
        for (int it = 0; it < 3; ++it) {
            int q = tid + it * 256;
            if (q < RR * 32) {
                int c = q & 31, row = q >> 5;
                int h = oy0 - 1 + row;
                const bool hok = (unsigned)h < (unsigned)HH;
                const float* src = x + (((size_t)(n * CIN + cbase + c) * HH + h) * WW) + (ox0 - 1);
                __hip_bfloat16* dst = xs + (row * RC) * CSTRIDE + c;
#pragma unroll
                for (int col = 0; col < RC; ++col) {
                    int wc = ox0 - 1 + col;
                    float v = 0.f;
                    if (hok && (unsigned)wc < (unsigned)WW) v = src[col];
                    dst[col * CSTRIDE] = __float2bfloat16(v);
                }
            }
        }
        __syncthreads();

#pragma unroll 1
        for (int off = 0; off < 9; ++off) {
            const int dy = (off * 11) >> 5;    // off/3
            const int dx = off - dy * 3;
            // A frags: wb[off][o][c], lane holds A[o=l15][k=lg*8+j]
            bf16x8 af[4];
            const __hip_bfloat16* wbase =
                wb + ((size_t)(off * COUT) + wo * 64 + l15) * CIN + cbase + lg * 8;
#pragma unroll
            for (int os = 0; os < 4; ++os)
                af[os] = *reinterpret_cast<const bf16x8*>(wbase + os * 16 * CIN);
            // B frags: xs[(py+dy)][(px+dx)][k], lane holds B[k=lg*8+j][p=l15]
            bf16x8 bfr[8];
#pragma unroll
            for (int ps = 0; ps < 8; ++ps) {
                int cell = (wp * 8 + ps + dy) * RC + (l15 + dx);
                bfr[ps] = *reinterpret_cast<const bf16x8*>(xs + cell * CSTRIDE + lg * 8);
            }
#pragma unroll
            for (int os = 0; os < 4; ++os)
#pragma unroll
                for (int ps = 0; ps < 8; ++ps)
                    acc[os][ps] = __builtin_amdgcn_mfma_f32_16x16x32_bf16(
                        af[os], bfr[ps], acc[os][ps], 0, 0, 0);
        }
    }

    // Epilogue: D row = o_local = lg*4 + r, col = p = l15 (within 16-wide subtile)
#pragma unroll
    for (int os = 0; os < 4; ++os) {
#pragma unroll
        for (int r = 0; r < 4; ++r) {
            int o = wo * 64 + os * 16 + lg * 4 + r;
            float bv = bias[o];
            float* obase = out + (((size_t)(n * COUT + o) * HH + oy0) * WW) + ox0 + l15;
#pragma unroll
            for (int ps = 0; ps < 8; ++ps) {
                int py = wp * 8 + ps;
                obase[py * WW] = acc[os][ps][r] + bv;
            }
        }
    }
}

extern "C" void kernel_launch(void* const* d_in, const int* in_sizes, int n_in,
                              void* d_out, int out_size, void* d_ws, size_t ws_size,
                              hipStream_t stream) {
    const float* x = (const float*)d_in[0];
    const float* w = (const float*)d_in[1];
    const float* bias = (const float*)d_in[2];
    float* out = (float*)d_out;
    __hip_bfloat16* wb = (__hip_bfloat16*)d_ws;   // 9*128*128*2 = 288 KB

    hipLaunchKernelGGL(wino_prep_weights, dim3(576), dim3(256), 0, stream, w, wb);
    hipLaunchKernelGGL(conv3x3_mfma, dim3(7, 7, 16), dim3(256), 0, stream,
                       x, wb, bias, out);
}

// Round 2
// 335.582 us; speedup vs baseline: 1.0908x; 1.0908x over previous
//
#include <hip/hip_runtime.h>
#include <hip/hip_bf16.h>

typedef __bf16 bf16x8 __attribute__((ext_vector_type(8)));
typedef float f32x4 __attribute__((ext_vector_type(4)));

#define HH 112
#define WW 112
#define CIN 128
#define COUT 128
#define HP 114          // padded H (pad=1 baked into xt)
#define WP 114

#define RRV 10          // staged rows (8 out + 2 halo)
#define RCV 18          // staged cols (16 out + 2 halo)
// LDS chunk: [RRV][RCV][32ch] bf16, linear, no pad (frag reads are contiguous 1024B)

// ---------------- weight repack: w[o][c][3][3] f32 -> wb[tap][o][c] bf16 ----
__global__ void wino_prep_weights(const float* __restrict__ w,
                                  __hip_bfloat16* __restrict__ wb) {
    int t = blockIdx.x * 256 + threadIdx.x;
    if (t >= 9 * COUT * CIN) return;
    int c = t & (CIN - 1);
    int o = (t >> 7) & (COUT - 1);
    int r = t >> 14;                       // tap 0..8
    wb[t] = __float2bfloat16(w[(o * CIN + c) * 9 + r]);
}

// ---------------- zero the pad border of xt ---------------------------------
__global__ void pad_borders(__hip_bfloat16* __restrict__ xt) {
    int q = blockIdx.x * 256 + threadIdx.x;       // 16B chunks over border cells
    int n = blockIdx.y;
    if (q >= 452 * 16) return;
    int chunk = q & 15;
    int cell = q >> 4;                            // 0..451
    int hp, wp;
    if (cell < 114)      { hp = 0;          wp = cell; }
    else if (cell < 228) { hp = 113;        wp = cell - 114; }
    else if (cell < 340) { hp = cell - 227; wp = 0; }      // 1..112
    else                 { hp = cell - 339; wp = 113; }    // 1..112
    bf16x8 z = {};
    *reinterpret_cast<bf16x8*>(xt + ((size_t)(n * HP + hp) * WP + wp) * CIN + chunk * 8) = z;
}

// ---------------- x[n][c][112][112] f32 -> xt[n][114][114][128] bf16 --------
// block: one (n, h, 16-w tile); 256 thr: wl = tid&15 (w), cg = tid>>4 (8-ch group)
__global__ __launch_bounds__(256) void transpose_pad(
        const float* __restrict__ x, __hip_bfloat16* __restrict__ xt) {
    const int wl = threadIdx.x & 15;
    const int cg = threadIdx.x >> 4;
    const int w = blockIdx.x * 16 + wl;
    const int h = blockIdx.y;
    const int n = blockIdx.z;
    const float* src = x + (((size_t)(n * CIN + cg * 8) * HH + h) * WW) + w;
    float v[8];
#pragma unroll
    for (int j = 0; j < 8; ++j) v[j] = src[(size_t)j * HH * WW];
    union { bf16x8 v8; __hip_bfloat16 e[8]; } o;
#pragma unroll
    for (int j = 0; j < 8; ++j) o.e[j] = __float2bfloat16(v[j]);
    *reinterpret_cast<bf16x8*>(
        xt + ((size_t)(n * HP + h + 1) * WP + (w + 1)) * CIN + cg * 8) = o.v8;
}

__device__ __forceinline__ void gload_lds16(const __hip_bfloat16* g, __hip_bfloat16* l) {
    __builtin_amdgcn_global_load_lds(
        (const __attribute__((address_space(1))) unsigned int*)g,
        (__attribute__((address_space(3))) unsigned int*)l, 16, 0, 0);
}

// ---------------- conv: implicit GEMM, 128 O x (16x8) px per block ----------
// 4 waves: wo = wv>>1 (64-O half), wp = wv&1 (4-row half). grid (7,14,16).
__global__ __launch_bounds__(256, 3) void conv3x3_mfma(
        const __hip_bfloat16* __restrict__ xt, const __hip_bfloat16* __restrict__ wb,
        const float* __restrict__ bias, float* __restrict__ out) {
    __shared__ __align__(16) __hip_bfloat16 xs[2][RRV * RCV * 32];

    const int ox0 = blockIdx.x * 16, oy0 = blockIdx.y * 8;
    const int n = blockIdx.z;
    const int tid = threadIdx.x;
    const int lane = tid & 63;
    const int wv = tid >> 6;
    const int wo = wv >> 1;
    const int wp = wv & 1;
    const int l15 = lane & 15;
    const int lg = lane >> 4;

    f32x4 acc[4][4];
#pragma unroll
    for (int i = 0; i < 4; ++i)
#pragma unroll
        for (int j = 0; j < 4; ++j) acc[i][j] = (f32x4){0.f, 0.f, 0.f, 0.f};

    // base of the block's padded input region (row 0 = oy0, col 0 = ox0)
    const __hip_bfloat16* gb0 = xt + (((size_t)n * HP + oy0) * WP + ox0) * CIN;

    // precompute this thread's staging (row,col,sub) triples: 720 quads
    int s_row[3], s_col[3], s_sub[3], s_act[3];
#pragma unroll
    for (int it = 0; it < 3; ++it) {
        int q = tid + it * 256;
        s_act[it] = (q < RRV * RCV * 4);
        int cell = q >> 2;
        int row = cell / RCV;
        s_row[it] = row;
        s_col[it] = cell - row * RCV;
        s_sub[it] = q & 3;
    }

    auto stage = [&](int buf, int cc) {
        const __hip_bfloat16* gb = gb0 + cc * 32;
#pragma unroll
        for (int it = 0; it < 3; ++it) {
            int q = tid + it * 256;
            if (s_act[it])
                gload_lds16(gb + ((size_t)(s_row[it] * WP + s_col[it])) * CIN + s_sub[it] * 8,
                            &xs[buf][q * 8]);
        }
    };

    stage(0, 0);
    __syncthreads();

#pragma unroll 1
    for (int cc = 0; cc < 4; ++cc) {
        if (cc < 3) stage((cc + 1) & 1, cc + 1);
        const int buf = cc & 1;
        const int cbase = cc * 32;
#pragma unroll
        for (int off = 0; off < 9; ++off) {
            const int dy = (off * 11) >> 5;
            const int dx = off - dy * 3;
            bf16x8 af[4];
            const __hip_bfloat16* wbase =
                wb + ((size_t)(off * COUT) + wo * 64 + l15) * CIN + cbase + lg * 8;
#pragma unroll
            for (int os = 0; os < 4; ++os)
                af[os] = *reinterpret_cast<const bf16x8*>(wbase + os * 16 * CIN);
            bf16x8 bfr[4];
#pragma unroll
            for (int ps = 0; ps < 4; ++ps) {
                int row = wp * 4 + ps + dy;
                int col = l15 + dx;
                bfr[ps] = *reinterpret_cast<const bf16x8*>(
                    &xs[buf][((row * RCV + col) * 32) + lg * 8]);
            }
#pragma unroll
            for (int os = 0; os < 4; ++os)
#pragma unroll
                for (int ps = 0; ps < 4; ++ps)
                    acc[os][ps] = __builtin_amdgcn_mfma_f32_16x16x32_bf16(
                        af[os], bfr[ps], acc[os][ps], 0, 0, 0);
        }
        __syncthreads();   // drains stage(cc+1) vmcnt + syncs buffer reuse
    }

    // epilogue: D col = px col = l15, D row = o_local = lg*4 + r
#pragma unroll
    for (int os = 0; os < 4; ++os) {
#pragma unroll
        for (int r = 0; r < 4; ++r) {
            int o = wo * 64 + os * 16 + lg * 4 + r;
            float bv = bias[o];
            float* obase = out + (((size_t)(n * COUT + o) * HH + oy0 + wp * 4) * WW) + ox0 + l15;
#pragma unroll
            for (int ps = 0; ps < 4; ++ps)
                obase[ps * WW] = acc[os][ps][r] + bv;
        }
    }
}

extern "C" void kernel_launch(void* const* d_in, const int* in_sizes, int n_in,
                              void* d_out, int out_size, void* d_ws, size_t ws_size,
                              hipStream_t stream) {
    const float* x = (const float*)d_in[0];
    const float* w = (const float*)d_in[1];
    const float* bias = (const float*)d_in[2];
    float* out = (float*)d_out;

    __hip_bfloat16* xt = (__hip_bfloat16*)d_ws;                       // 16*114*114*128*2 = 53,231,616 B
    __hip_bfloat16* wb = (__hip_bfloat16*)((char*)d_ws + 53231616);   // 294,912 B

    hipLaunchKernelGGL(wino_prep_weights, dim3(576), dim3(256), 0, stream, w, wb);
    hipLaunchKernelGGL(pad_borders, dim3((452 * 16 + 255) / 256, 16), dim3(256), 0, stream, xt);
    hipLaunchKernelGGL(transpose_pad, dim3(7, 112, 16), dim3(256), 0, stream, x, xt);
    hipLaunchKernelGGL(conv3x3_mfma, dim3(7, 14, 16), dim3(256), 0, stream,
                       xt, wb, bias, out);
}